// Round 6
// baseline (245.042 us; speedup 1.0000x reference)
//
#include <hip/hip_runtime.h>

#define NN 100000
#define NG 512
#define NCH 128
#define EPSV 0.001f
#define NCHUNK 13        // 1 (x0) + 3 (x1) + 9 (x2) chunks of 32 float4 slots
#define NT 512           // 32 slots x 16 phases
#define RCAP 16          // staged nodes per thread: covers 256 nodes/graph
#define OFF1 12800000L
#define OFF2 51200000L

typedef float f32x4 __attribute__((ext_vector_type(4)));

// ---- graph start offsets: parallel boundary scan over sorted batch ----
__global__ __launch_bounds__(256) void k_offsets(const int* __restrict__ b32,
                                                 int* __restrict__ start) {
  int i = blockIdx.x * 256 + threadIdx.x;
  if (i >= NN) return;
  // int64 layout: odd int32 words are zero hi-words -> b32[NN-1] (odd idx) == 0.
  bool is64 = (b32[NN - 1] == 0);
  int cur  = is64 ? b32[2 * i] : b32[i];
  int prev = (i == 0) ? -1 : (is64 ? b32[2 * (i - 1)] : b32[i - 1]);
  for (int g = prev + 1; g <= cur; ++g) start[g] = i;
  if (i == 0) start[NG] = NN;
}

template<int STRIDE>
static __device__ __forceinline__ void body(
    const float* __restrict__ src, float* __restrict__ dst,
    int cbase, int gcomp0,
    const float* __restrict__ alpha, const float* __restrict__ beta,
    const float* __restrict__ gamma, int ns, int ne,
    float (*red)[32][9]) {
  int t  = threadIdx.x;
  int s  = t & 31;          // float4 slot within chunk (0..31)
  int ph = t >> 5;          // node phase (0..15)
  int cnt = ne - ns;
  float invd = 1.0f / (float)cnt;
  long coloff = (long)cbase + (s << 2);
  const float* p0 = src + (long)ns * STRIDE + coloff;

  // ---- pass 1: clamped staged loads + weighted accumulate (no branches) ----
  float s0=0,s1=0,s2=0,s3=0, q0=0,q1=0,q2=0,q3=0;
  f32x4 v[RCAP];
  #pragma unroll
  for (int i = 0; i < RCAP; ++i) {
    int n = ph + (i << 4);
    int ncl = (n < cnt) ? n : cnt - 1;
    float w = (n < cnt) ? 1.0f : 0.0f;
    f32x4 u = __builtin_nontemporal_load(
        reinterpret_cast<const f32x4*>(p0 + (long)ncl * STRIDE));
    v[i] = u;
    float wx = w*u.x, wy = w*u.y, wz = w*u.z, ww = w*u.w;
    s0 += wx; s1 += wy; s2 += wz; s3 += ww;
    q0 += wx*u.x; q1 += wy*u.y; q2 += wz*u.z; q3 += ww*u.w;
  }
  // overflow (graphs > 256 nodes): accumulate unstaged
  for (int n = ph + (RCAP << 4); n < cnt; n += 16) {
    f32x4 u = __builtin_nontemporal_load(
        reinterpret_cast<const f32x4*>(p0 + (long)n * STRIDE));
    s0 += u.x; s1 += u.y; s2 += u.z; s3 += u.w;
    q0 += u.x*u.x; q1 += u.y*u.y; q2 += u.z*u.z; q3 += u.w*u.w;
  }

  // ---- reduce 16 phases: shfl ^32 in-wave, LDS across 8 waves ----
  #define RED1(x) { x += __shfl_xor(x, 32); }
  RED1(s0) RED1(s1) RED1(s2) RED1(s3) RED1(q0) RED1(q1) RED1(q2) RED1(q3)
  #undef RED1
  int w = t >> 6, l = t & 63;
  if (l < 32) {
    red[w][l][0]=s0; red[w][l][1]=s1; red[w][l][2]=s2; red[w][l][3]=s3;
    red[w][l][4]=q0; red[w][l][5]=q1; red[w][l][6]=q2; red[w][l][7]=q3;
  }
  __syncthreads();

  float S[4] = {0,0,0,0}, Q[4] = {0,0,0,0};
  #pragma unroll
  for (int ww2 = 0; ww2 < 8; ++ww2) {
    #pragma unroll
    for (int j = 0; j < 4; ++j) {
      S[j] += red[ww2][s][j];
      Q[j] += red[ww2][s][j+4];
    }
  }

  // ---- A = alpha*mean, B = gamma*rsqrt(var+eps), beta (way 0 only) ----
  float A[4], Bv[4], Be[4];
  #pragma unroll
  for (int j = 0; j < 4; ++j) {
    int c = gcomp0 + (s << 2) + j;
    int way, ch;
    if (c < 128)      { way = 0; ch = c; }
    else if (c < 512) { way = 1; ch = (c - 128) / 3; }
    else              { way = 2; ch = (c - 512) / 9; }
    float a  = alpha[way * NCH + ch];
    float gm = gamma[way * NCH + ch];
    float m  = S[j] * invd;
    float var = Q[j] * invd - m * m * a * (2.0f - a);  // E[(x - a*m)^2]
    A[j]  = m * a;
    Bv[j] = gm * rsqrtf(var + EPSV);
    Be[j] = (c < 128) ? beta[c] : 0.0f;
  }

  // ---- pass 2: apply from registers, guarded nontemporal stores ----
  float* d0 = dst + (long)ns * STRIDE + coloff;
  #pragma unroll
  for (int i = 0; i < RCAP; ++i) {
    int n = ph + (i << 4);
    if (n < cnt) {
      f32x4 u = v[i], o;
      o.x = (u.x - A[0]) * Bv[0] + Be[0];
      o.y = (u.y - A[1]) * Bv[1] + Be[1];
      o.z = (u.z - A[2]) * Bv[2] + Be[2];
      o.w = (u.w - A[3]) * Bv[3] + Be[3];
      __builtin_nontemporal_store(o,
          reinterpret_cast<f32x4*>(d0 + (long)n * STRIDE));
    }
  }
  for (int n = ph + (RCAP << 4); n < cnt; n += 16) {
    f32x4 u = __builtin_nontemporal_load(
        reinterpret_cast<const f32x4*>(p0 + (long)n * STRIDE));
    f32x4 o;
    o.x = (u.x - A[0]) * Bv[0] + Be[0];
    o.y = (u.y - A[1]) * Bv[1] + Be[1];
    o.z = (u.z - A[2]) * Bv[2] + Be[2];
    o.w = (u.w - A[3]) * Bv[3] + Be[3];
    __builtin_nontemporal_store(o,
        reinterpret_cast<f32x4*>(d0 + (long)n * STRIDE));
  }
}

__global__ __launch_bounds__(NT, 4) void k_fused(
    const float* __restrict__ x0, const float* __restrict__ x1,
    const float* __restrict__ x2, const float* __restrict__ alpha,
    const float* __restrict__ beta, const float* __restrict__ gamma,
    const int* __restrict__ start, float* __restrict__ out) {
  __shared__ float red[8][32][9];
  int bid = blockIdx.x;
  int g = bid / NCHUNK;
  int k = bid - g * NCHUNK;
  int ns = start[g], ne = start[g + 1];

  if (k == 0)
    body<128>(x0, out, 0, 0, alpha, beta, gamma, ns, ne, red);
  else if (k < 4)
    body<384>(x1, out + OFF1, (k - 1) * 128, 128 + (k - 1) * 128,
              alpha, beta, gamma, ns, ne, red);
  else
    body<1152>(x2, out + OFF2, (k - 4) * 128, 512 + (k - 4) * 128,
               alpha, beta, gamma, ns, ne, red);
}

extern "C" void kernel_launch(void* const* d_in, const int* in_sizes, int n_in,
                              void* d_out, int out_size, void* d_ws, size_t ws_size,
                              hipStream_t stream) {
  const float* x0    = (const float*)d_in[0];
  const float* x1    = (const float*)d_in[1];
  const float* x2    = (const float*)d_in[2];
  const float* alpha = (const float*)d_in[3];
  const float* beta  = (const float*)d_in[4];
  const float* gamma = (const float*)d_in[5];
  const int*   b32   = (const int*)d_in[6];   // batch: int32 or int64 (device-detected)
  float* out = (float*)d_out;

  int* start = (int*)d_ws;  // 513 ints

  k_offsets<<<(NN + 255) / 256, 256, 0, stream>>>(b32, start);
  k_fused<<<NG * NCHUNK, NT, 0, stream>>>(x0, x1, x2, alpha, beta, gamma, start, out);
}

// Round 7
// 242.453 us; speedup vs baseline: 1.0107x; 1.0107x over previous
//
#include <hip/hip_runtime.h>

#define NN 100000
#define NG 512
#define NCH 128
#define EPSV 0.001f
#define NCHUNK 26        // 2 (x0) + 6 (x1) + 18 (x2) chunks of 16 float4 slots
#define NT 256
#define RCAP 16          // staged nodes per thread: covers 256 nodes/graph
#define OFF1 12800000L
#define OFF2 51200000L

typedef float f32x4 __attribute__((ext_vector_type(4)));

// ---- graph start offsets: parallel boundary scan over sorted batch ----
__global__ __launch_bounds__(NT) void k_offsets(const int* __restrict__ b32,
                                                int* __restrict__ start) {
  int i = blockIdx.x * NT + threadIdx.x;
  if (i >= NN) return;
  // int64 layout: odd int32 words are zero hi-words -> b32[NN-1] (odd idx) == 0.
  bool is64 = (b32[NN - 1] == 0);
  int cur  = is64 ? b32[2 * i] : b32[i];
  int prev = (i == 0) ? -1 : (is64 ? b32[2 * (i - 1)] : b32[i - 1]);
  for (int g = prev + 1; g <= cur; ++g) start[g] = i;
  if (i == 0) start[NG] = NN;
}

template<int STRIDE>
static __device__ __forceinline__ void body(
    const float* __restrict__ src, float* __restrict__ dst,
    int cbase, int gcomp0,
    const float* __restrict__ alpha, const float* __restrict__ beta,
    const float* __restrict__ gamma, int ns, int ne,
    float (*red)[16][8]) {
  int t  = threadIdx.x;
  int s  = t & 15;          // float4 slot within chunk (0..15)
  int ph = t >> 4;          // node phase (0..15)
  float invd = 1.0f / (float)(ne - ns);
  long coloff = (long)cbase + (s << 2);
  const float* p0 = src + (long)(ns + ph) * STRIDE + coloff;

  // ---- pass 1: staged loads + accumulate (compile-time stride) ----
  float s0=0,s1=0,s2=0,s3=0, q0=0,q1=0,q2=0,q3=0;
  f32x4 v[RCAP];
  #pragma unroll
  for (int i = 0; i < RCAP; ++i) {
    if (ns + ph + (i << 4) < ne) {
      f32x4 u = __builtin_nontemporal_load(
          reinterpret_cast<const f32x4*>(p0 + (long)i * 16 * STRIDE));
      v[i] = u;
      s0 += u.x; s1 += u.y; s2 += u.z; s3 += u.w;
      q0 += u.x*u.x; q1 += u.y*u.y; q2 += u.z*u.z; q3 += u.w*u.w;
    }
  }
  // overflow (graphs > 256 nodes): accumulate unstaged
  for (int n = ns + ph + (RCAP << 4); n < ne; n += 16) {
    f32x4 u = __builtin_nontemporal_load(
        reinterpret_cast<const f32x4*>(src + (long)n * STRIDE + coloff));
    s0 += u.x; s1 += u.y; s2 += u.z; s3 += u.w;
    q0 += u.x*u.x; q1 += u.y*u.y; q2 += u.z*u.z; q3 += u.w*u.w;
  }

  // ---- reduce over 16 phases: shfl ^16,^32 in-wave, LDS across 4 waves ----
  #define RED2(x) { x += __shfl_xor(x, 16); x += __shfl_xor(x, 32); }
  RED2(s0) RED2(s1) RED2(s2) RED2(s3) RED2(q0) RED2(q1) RED2(q2) RED2(q3)
  #undef RED2
  int w = t >> 6, l = t & 63;
  if (l < 16) {
    red[w][l][0]=s0; red[w][l][1]=s1; red[w][l][2]=s2; red[w][l][3]=s3;
    red[w][l][4]=q0; red[w][l][5]=q1; red[w][l][6]=q2; red[w][l][7]=q3;
  }
  __syncthreads();

  float S[4], Q[4];
  #pragma unroll
  for (int j = 0; j < 4; ++j) {
    S[j] = red[0][s][j]   + red[1][s][j]   + red[2][s][j]   + red[3][s][j];
    Q[j] = red[0][s][j+4] + red[1][s][j+4] + red[2][s][j+4] + red[3][s][j+4];
  }

  // ---- A = alpha*mean, B = gamma*rsqrt(var+eps), beta (way 0 only) ----
  float A[4], Bv[4], Be[4];
  #pragma unroll
  for (int j = 0; j < 4; ++j) {
    int c = gcomp0 + (s << 2) + j;
    int way, ch;
    if (c < 128)      { way = 0; ch = c; }
    else if (c < 512) { way = 1; ch = (c - 128) / 3; }
    else              { way = 2; ch = (c - 512) / 9; }
    float a  = alpha[way * NCH + ch];
    float gm = gamma[way * NCH + ch];
    float m  = S[j] * invd;
    float var = Q[j] * invd - m * m * a * (2.0f - a);  // E[(x - a*m)^2]
    A[j]  = m * a;
    Bv[j] = gm * rsqrtf(var + EPSV);
    Be[j] = (c < 128) ? beta[c] : 0.0f;
  }

  // ---- pass 2: apply from registers, nontemporal stores ----
  float* q0p = dst + (long)(ns + ph) * STRIDE + coloff;
  #pragma unroll
  for (int i = 0; i < RCAP; ++i) {
    if (ns + ph + (i << 4) < ne) {
      f32x4 u = v[i], o;
      o.x = (u.x - A[0]) * Bv[0] + Be[0];
      o.y = (u.y - A[1]) * Bv[1] + Be[1];
      o.z = (u.z - A[2]) * Bv[2] + Be[2];
      o.w = (u.w - A[3]) * Bv[3] + Be[3];
      __builtin_nontemporal_store(o,
          reinterpret_cast<f32x4*>(q0p + (long)i * 16 * STRIDE));
    }
  }
  for (int n = ns + ph + (RCAP << 4); n < ne; n += 16) {
    f32x4 u = __builtin_nontemporal_load(
        reinterpret_cast<const f32x4*>(src + (long)n * STRIDE + coloff));
    f32x4 o;
    o.x = (u.x - A[0]) * Bv[0] + Be[0];
    o.y = (u.y - A[1]) * Bv[1] + Be[1];
    o.z = (u.z - A[2]) * Bv[2] + Be[2];
    o.w = (u.w - A[3]) * Bv[3] + Be[3];
    __builtin_nontemporal_store(o,
        reinterpret_cast<f32x4*>(dst + (long)n * STRIDE + coloff));
  }
}

__global__ __launch_bounds__(NT) void k_fused(
    const float* __restrict__ x0, const float* __restrict__ x1,
    const float* __restrict__ x2, const float* __restrict__ alpha,
    const float* __restrict__ beta, const float* __restrict__ gamma,
    const int* __restrict__ start, float* __restrict__ out) {
  __shared__ float red[4][16][8];
  int bid = blockIdx.x;
  int g = bid / NCHUNK;
  int k = bid - g * NCHUNK;
  int ns = start[g], ne = start[g + 1];

  if (k < 2)
    body<128>(x0, out, k * 64, k * 64, alpha, beta, gamma, ns, ne, red);
  else if (k < 8)
    body<384>(x1, out + OFF1, (k - 2) * 64, 128 + (k - 2) * 64,
              alpha, beta, gamma, ns, ne, red);
  else
    body<1152>(x2, out + OFF2, (k - 8) * 64, 512 + (k - 8) * 64,
               alpha, beta, gamma, ns, ne, red);
}

extern "C" void kernel_launch(void* const* d_in, const int* in_sizes, int n_in,
                              void* d_out, int out_size, void* d_ws, size_t ws_size,
                              hipStream_t stream) {
  const float* x0    = (const float*)d_in[0];
  const float* x1    = (const float*)d_in[1];
  const float* x2    = (const float*)d_in[2];
  const float* alpha = (const float*)d_in[3];
  const float* beta  = (const float*)d_in[4];
  const float* gamma = (const float*)d_in[5];
  const int*   b32   = (const int*)d_in[6];   // batch: int32 or int64 (device-detected)
  float* out = (float*)d_out;

  int* start = (int*)d_ws;  // 513 ints

  k_offsets<<<(NN + NT - 1) / NT, NT, 0, stream>>>(b32, start);
  k_fused<<<NG * NCHUNK, NT, 0, stream>>>(x0, x1, x2, alpha, beta, gamma, start, out);
}